// Round 1
// baseline (102.114 us; speedup 1.0000x reference)
//
#include <hip/hip_runtime.h>
#include <math.h>

#define K_DIM 4096
#define BSZ 32768
#define BLOCK 256
#define WAVES (BLOCK / 64)

// One block per row: load 4096 fp32 into registers (16/thread), reduce max,
// then sum of exp(x - max) from registers (single HBM pass), emit per-row loss.
__global__ __launch_bounds__(BLOCK) void row_loss_kernel(
    const float* __restrict__ x, float* __restrict__ loss_out) {
  __shared__ float s_red[WAVES];

  const int row = blockIdx.x;
  const int t = threadIdx.x;
  const float4* xr = reinterpret_cast<const float4*>(x) + (size_t)row * (K_DIM / 4);

  float4 v[4];
#pragma unroll
  for (int i = 0; i < 4; ++i) v[i] = xr[i * BLOCK + t];  // coalesced 16B/lane

  // thread 0's v[0].x is x[row][0]
  const float x0 = v[0].x;

  // per-thread max over 16 values
  float m = v[0].x;
#pragma unroll
  for (int i = 0; i < 4; ++i) {
    m = fmaxf(m, fmaxf(fmaxf(v[i].x, v[i].y), fmaxf(v[i].z, v[i].w)));
  }
  // wave (64-lane) max reduce
#pragma unroll
  for (int off = 32; off >= 1; off >>= 1) m = fmaxf(m, __shfl_xor(m, off));

  const int wave = t >> 6;
  const int lane = t & 63;
  if (lane == 0) s_red[wave] = m;
  __syncthreads();
  const float rowmax =
      fmaxf(fmaxf(s_red[0], s_red[1]), fmaxf(s_red[2], s_red[3]));
  __syncthreads();  // s_red reused below

  // sum of exp(x - rowmax) from registers
  float s = 0.f;
#pragma unroll
  for (int i = 0; i < 4; ++i) {
    s += __expf(v[i].x - rowmax);
    s += __expf(v[i].y - rowmax);
    s += __expf(v[i].z - rowmax);
    s += __expf(v[i].w - rowmax);
  }
#pragma unroll
  for (int off = 32; off >= 1; off >>= 1) s += __shfl_xor(s, off);
  if (lane == 0) s_red[wave] = s;
  __syncthreads();

  if (t == 0) {
    float total = s_red[0] + s_red[1] + s_red[2] + s_red[3];
    loss_out[row] = rowmax + __logf(total) - x0;
  }
}

// Single-block deterministic masked mean over the 32768 per-row losses.
__global__ __launch_bounds__(1024) void finalize_kernel(
    const float* __restrict__ loss, const float* __restrict__ thr_p,
    float* __restrict__ out) {
  __shared__ float s_sum[1024 / 64];
  __shared__ float s_cnt[1024 / 64];

  const float thr = *thr_p;
  const int t = threadIdx.x;

  float sum = 0.f, cnt = 0.f;
  for (int i = t; i < BSZ; i += 1024) {
    float l = loss[i];
    if (l > thr) {
      sum += l;
      cnt += 1.f;
    }
  }
#pragma unroll
  for (int off = 32; off >= 1; off >>= 1) {
    sum += __shfl_xor(sum, off);
    cnt += __shfl_xor(cnt, off);
  }
  const int wave = t >> 6;
  const int lane = t & 63;
  if (lane == 0) {
    s_sum[wave] = sum;
    s_cnt[wave] = cnt;
  }
  __syncthreads();
  if (t == 0) {
    float S = 0.f, C = 0.f;
#pragma unroll
    for (int w = 0; w < 1024 / 64; ++w) {
      S += s_sum[w];
      C += s_cnt[w];
    }
    out[0] = (C == 0.f) ? loss[0] : S / fmaxf(C, 1.f);
  }
}

extern "C" void kernel_launch(void* const* d_in, const int* in_sizes, int n_in,
                              void* d_out, int out_size, void* d_ws,
                              size_t ws_size, hipStream_t stream) {
  const float* x = (const float*)d_in[0];
  const float* thr = (const float*)d_in[1];
  float* out = (float*)d_out;
  float* loss = (float*)d_ws;  // 32768 floats = 128 KB scratch

  row_loss_kernel<<<BSZ, BLOCK, 0, stream>>>(x, loss);
  finalize_kernel<<<1, 1024, 0, stream>>>(loss, thr, out);
}

// Round 2
// 93.106 us; speedup vs baseline: 1.0967x; 1.0967x over previous
//
#include <hip/hip_runtime.h>
#include <math.h>

#define K_DIM 4096
#define BSZ 32768
#define BLOCK 256
#define WAVES_PER_BLOCK (BLOCK / 64)
#define ROWS_PER_WAVE 4
#define GRID (BSZ / (WAVES_PER_BLOCK * ROWS_PER_WAVE))  // 2048 blocks

typedef float f32x4 __attribute__((ext_vector_type(4)));

// Wave-per-row, zero barriers: each 64-lane wave loads one full row (16
// float4 / lane, nontemporal), reduces max and sum-of-exp with shfl_xor
// butterflies only. 4 consecutive rows per wave.
__global__ __launch_bounds__(BLOCK) void row_loss_kernel(
    const float* __restrict__ x, float* __restrict__ loss_out) {
  const int t = threadIdx.x;
  const int lane = t & 63;
  const int gw = blockIdx.x * WAVES_PER_BLOCK + (t >> 6);  // global wave id

  const f32x4* x4 = reinterpret_cast<const f32x4*>(x);

#pragma unroll
  for (int r = 0; r < ROWS_PER_WAVE; ++r) {
    const int row = gw * ROWS_PER_WAVE + r;
    const f32x4* xr = x4 + (size_t)row * (K_DIM / 4);

    f32x4 v[16];
#pragma unroll
    for (int i = 0; i < 16; ++i) {
      v[i] = __builtin_nontemporal_load(xr + i * 64 + lane);  // coalesced 16B/lane
    }

    const float x0 = v[0].x;  // on lane 0 this is x[row][0]

    // per-lane max over 64 values
    float m = v[0].x;
#pragma unroll
    for (int i = 0; i < 16; ++i) {
      m = fmaxf(m, fmaxf(fmaxf(v[i].x, v[i].y), fmaxf(v[i].z, v[i].w)));
    }
    // 64-lane butterfly max (no barrier)
#pragma unroll
    for (int off = 32; off >= 1; off >>= 1) m = fmaxf(m, __shfl_xor(m, off));

    // sum of exp(x - m) from registers
    float s = 0.f;
#pragma unroll
    for (int i = 0; i < 16; ++i) {
      s += __expf(v[i].x - m) + __expf(v[i].y - m) + __expf(v[i].z - m) +
           __expf(v[i].w - m);
    }
#pragma unroll
    for (int off = 32; off >= 1; off >>= 1) s += __shfl_xor(s, off);

    if (lane == 0) loss_out[row] = m + __logf(s) - x0;
  }
}

// Single-block deterministic masked mean over the 32768 per-row losses.
__global__ __launch_bounds__(1024) void finalize_kernel(
    const float* __restrict__ loss, const float* __restrict__ thr_p,
    float* __restrict__ out) {
  __shared__ float s_sum[1024 / 64];
  __shared__ float s_cnt[1024 / 64];

  const float thr = *thr_p;
  const int t = threadIdx.x;
  const f32x4* l4 = reinterpret_cast<const f32x4*>(loss);

  float sum = 0.f, cnt = 0.f;
#pragma unroll
  for (int i = 0; i < BSZ / 4 / 1024; ++i) {  // 8 x float4 per thread
    f32x4 v = l4[i * 1024 + t];
#pragma unroll
    for (int j = 0; j < 4; ++j) {
      float l = v[j];
      if (l > thr) {
        sum += l;
        cnt += 1.f;
      }
    }
  }
#pragma unroll
  for (int off = 32; off >= 1; off >>= 1) {
    sum += __shfl_xor(sum, off);
    cnt += __shfl_xor(cnt, off);
  }
  const int wave = t >> 6;
  const int lane = t & 63;
  if (lane == 0) {
    s_sum[wave] = sum;
    s_cnt[wave] = cnt;
  }
  __syncthreads();
  if (t == 0) {
    float S = 0.f, C = 0.f;
#pragma unroll
    for (int w = 0; w < 1024 / 64; ++w) {
      S += s_sum[w];
      C += s_cnt[w];
    }
    out[0] = (C == 0.f) ? loss[0] : S / fmaxf(C, 1.f);
  }
}

extern "C" void kernel_launch(void* const* d_in, const int* in_sizes, int n_in,
                              void* d_out, int out_size, void* d_ws,
                              size_t ws_size, hipStream_t stream) {
  const float* x = (const float*)d_in[0];
  const float* thr = (const float*)d_in[1];
  float* out = (float*)d_out;
  float* loss = (float*)d_ws;  // 32768 floats = 128 KB scratch

  row_loss_kernel<<<GRID, BLOCK, 0, stream>>>(x, loss);
  finalize_kernel<<<1, 1024, 0, stream>>>(loss, thr, out);
}